// Round 10
// baseline (1168.669 us; speedup 1.0000x reference)
//
#include <hip/hip_runtime.h>

typedef __bf16 bf16_t;
typedef bf16_t bf16x4 __attribute__((ext_vector_type(4)));
typedef bf16_t bf16x8 __attribute__((ext_vector_type(8)));
typedef float floatx4 __attribute__((ext_vector_type(4)));

#define EPSF 1e-5f
#define DEV static __device__ __forceinline__

// ---------------------------------------------------------------------------
// K0: swizzle weight matrices (f32 [K][128]) into B-fragment order, bf16.
// sw[((t*nK + s)*64 + l)*8 + j] = W[(s*32 + (l>>4)*8 + j)*128 + (t*16 + (l&15))]
// Layout ranges (bf16 elems): W_in@0(16384), W_ctx1@16384(32768),
// W_ctx2@49152(16384), W_m1@65536(16384), W_m2@81920(16384). Total 98304.
// ---------------------------------------------------------------------------
__global__ __launch_bounds__(256) void k_prep(
    const float* __restrict__ W_in, const float* __restrict__ W_ctx1,
    const float* __restrict__ W_ctx2, const float* __restrict__ W_m1,
    const float* __restrict__ W_m2, bf16_t* __restrict__ sw)
{
    int idx = blockIdx.x * 256 + threadIdx.x;   // grid sized to exactly 98304
    const float* W; int base, ks;
    if (idx < 16384)      { W = W_in;   base = 0;     ks = 2; }
    else if (idx < 49152) { W = W_ctx1; base = 16384; ks = 3; }
    else if (idx < 65536) { W = W_ctx2; base = 49152; ks = 2; }
    else if (idx < 81920) { W = W_m1;   base = 65536; ks = 2; }
    else                  { W = W_m2;   base = 81920; ks = 2; }
    int local = idx - base;
    int j = local & 7, l = (local >> 3) & 63, rest = local >> 9;
    int s = rest & ((1 << ks) - 1), t = rest >> ks;
    int k = s * 32 + (l >> 4) * 8 + j;
    int n = t * 16 + (l & 15);
    sw[idx] = (bf16_t)W[k * 128 + n];
}

// GroupNorm over 128 channels per row, operating on MFMA C-layout accumulators.
// acc[t][rr] holds element (row = (lane>>4)*4+rr, col = t*16 + (lane&15)).
DEV void gn_rows(floatx4* acc, int lane, const float* __restrict__ gamma,
                 const float* __restrict__ beta, bool do_relu)
{
    int m = lane & 15;
    float s1[4] = {0.f,0.f,0.f,0.f}, s2[4] = {0.f,0.f,0.f,0.f};
#pragma unroll
    for (int t = 0; t < 8; ++t)
#pragma unroll
        for (int rr = 0; rr < 4; ++rr) { float v = acc[t][rr]; s1[rr] += v; s2[rr] += v*v; }
#pragma unroll
    for (int mask = 1; mask <= 8; mask <<= 1)
#pragma unroll
        for (int rr = 0; rr < 4; ++rr) {
            s1[rr] += __shfl_xor(s1[rr], mask);
            s2[rr] += __shfl_xor(s2[rr], mask);
        }
    float mean[4], inv[4];
#pragma unroll
    for (int rr = 0; rr < 4; ++rr) {
        mean[rr] = s1[rr] * (1.f/128.f);
        float var = s2[rr] * (1.f/128.f) - mean[rr]*mean[rr];
        inv[rr] = rsqrtf(var + EPSF);
    }
#pragma unroll
    for (int t = 0; t < 8; ++t) {
        int n = t*16 + m;
        float ga = gamma[n], be = beta[n];
#pragma unroll
        for (int rr = 0; rr < 4; ++rr) {
            float v = (acc[t][rr] - mean[rr]) * inv[rr] * ga + be;
            acc[t][rr] = do_relu ? fmaxf(v, 0.f) : v;
        }
    }
}

// ---------------------------------------------------------------------------
// Binning: histogram of wi, HIERARCHICAL exclusive scan -> off[Nt+1], then a
// massive-TLP slot-assignment kernel writing dst[e].
// ---------------------------------------------------------------------------
__global__ __launch_bounds__(256) void k_count(const int* __restrict__ idxs,
                                               int* __restrict__ cnt, int E)
{
    int e = blockIdx.x * 256 + threadIdx.x;
    if (e < E) atomicAdd(&cnt[idxs[e]], 1);
}

// scan stage A: each block exclusive-scans its 4096 elements, emits block sum
__global__ __launch_bounds__(1024) void k_scanA(const int* __restrict__ cnt,
                                                int* __restrict__ off,
                                                int* __restrict__ bsum, int N)
{
    __shared__ int wsum[16];
    int tid = threadIdx.x, lane = tid & 63, wid = tid >> 6;
    int i0 = blockIdx.x * 4096 + tid * 4;
    int v0 = 0, v1 = 0, v2 = 0, v3 = 0;
    if (i0 + 3 < N) {
        int4 v = *(const int4*)(cnt + i0);
        v0 = v.x; v1 = v.y; v2 = v.z; v3 = v.w;
    } else {
        if (i0     < N) v0 = cnt[i0];
        if (i0 + 1 < N) v1 = cnt[i0+1];
        if (i0 + 2 < N) v2 = cnt[i0+2];
        if (i0 + 3 < N) v3 = cnt[i0+3];
    }
    int tot = v0 + v1 + v2 + v3;
    int x = tot;
#pragma unroll
    for (int d = 1; d < 64; d <<= 1) {
        int y = __shfl_up(x, d);
        if (lane >= d) x += y;
    }
    if (lane == 63) wsum[wid] = x;
    __syncthreads();
    if (wid == 0) {
        int wv = (lane < 16) ? wsum[lane] : 0;
#pragma unroll
        for (int d = 1; d < 16; d <<= 1) {
            int y = __shfl_up(wv, d);
            if (lane >= d) wv += y;
        }
        if (lane < 16) wsum[lane] = wv;
    }
    __syncthreads();
    int ebase = ((wid > 0) ? wsum[wid-1] : 0) + (x - tot);
    if (i0 + 3 < N) {
        *(int4*)(off + i0) = make_int4(ebase, ebase+v0, ebase+v0+v1, ebase+v0+v1+v2);
    } else {
        if (i0     < N) off[i0]   = ebase;
        if (i0 + 1 < N) off[i0+1] = ebase + v0;
        if (i0 + 2 < N) off[i0+2] = ebase + v0 + v1;
        if (i0 + 3 < N) off[i0+3] = ebase + v0 + v1 + v2;
    }
    if (tid == 0) bsum[blockIdx.x] = wsum[15];
}

// scan stage B: exclusive-scan the (<=1024) block sums in place; off[N] = total
__global__ __launch_bounds__(1024) void k_scanB(int* __restrict__ bsum,
                                                int* __restrict__ off,
                                                int NB, int N)
{
    __shared__ int wsum[16];
    int tid = threadIdx.x, lane = tid & 63, wid = tid >> 6;
    int v = (tid < NB) ? bsum[tid] : 0;
    int x = v;
#pragma unroll
    for (int d = 1; d < 64; d <<= 1) {
        int y = __shfl_up(x, d);
        if (lane >= d) x += y;
    }
    if (lane == 63) wsum[wid] = x;
    __syncthreads();
    if (wid == 0) {
        int wv = (lane < 16) ? wsum[lane] : 0;
#pragma unroll
        for (int d = 1; d < 16; d <<= 1) {
            int y = __shfl_up(wv, d);
            if (lane >= d) wv += y;
        }
        if (lane < 16) wsum[lane] = wv;
    }
    __syncthreads();
    int excl = ((wid > 0) ? wsum[wid-1] : 0) + (x - v);
    if (tid < NB) bsum[tid] = excl;
    if (tid == 0) off[N] = wsum[15];
}

// scan stage C: add block carries
__global__ __launch_bounds__(256) void k_scanC(int* __restrict__ off,
                                               const int* __restrict__ bsum, int N)
{
    int i = blockIdx.x * 256 + threadIdx.x;
    if (i < N) off[i] += bsum[i >> 12];
}

// slot assignment: one atomic per THREAD at full occupancy -> latency hidden
__global__ __launch_bounds__(256) void k_slots(const int* __restrict__ wi,
                                               const int* __restrict__ off,
                                               int* __restrict__ cur,
                                               int* __restrict__ dst, int E)
{
    int e = blockIdx.x * 256 + threadIdx.x;
    if (e < E) {
        int w = wi[e];
        dst[e] = off[w] + atomicAdd(&cur[w], 1);
    }
}

// ---------------------------------------------------------------------------
// K2 (v9b): identical to round-9 k_edge9 EXCEPT the explicit occupancy pin
// __launch_bounds__(1024, 4): 16 waves/block = 4 waves/EU = 1 block/CU ->
// VGPR cap 128 (live set ~90 fits; round-9's implicit cap of 64 spilled
// 1.6 GB of scratch traffic and inflated the kernel to 910 us).
// B-fragments come from LDS (ds_read_b128) instead of a latency-serialized
// 64-deep L1/L2 load chain.
// ---------------------------------------------------------------------------
__global__ __launch_bounds__(1024, 4) void k_edge9(
    const float* __restrict__ cfeat, const float* __restrict__ cpose,
    const float* __restrict__ tpose, const int* __restrict__ hi,
    const int* __restrict__ wi, const int* __restrict__ dst,
    const float* __restrict__ W_rp,
    const float* __restrict__ b_rp, const float* __restrict__ g_ctx,
    const float* __restrict__ be_ctx, const bf16_t* __restrict__ swC1,
    bf16_t* __restrict__ hbuf, int E)
{
    __shared__ alignas(16) bf16_t sB[32768];     // full swC1, B-fragment order
    __shared__ alignas(16) bf16_t sH[16][2176];  // per-wave [16][136] restage
    int tid = threadIdx.x, lane = tid & 63, wave = tid >> 6;
    int r = lane & 15, g = lane >> 4;
    int r2 = lane >> 2, c2 = lane & 3;

    // one-time cooperative stage of swC1 -> LDS (4 x 16B per thread)
    {
        const bf16x8* gsrc = (const bf16x8*)swC1;
        bf16x8* ldst = (bf16x8*)sB;
#pragma unroll
        for (int i = 0; i < 4; ++i)
            ldst[i * 1024 + tid] = gsrc[i * 1024 + tid];
    }
    __syncthreads();

    int ntiles = (E + 15) >> 4;
    for (int tile = blockIdx.x * 16 + wave; tile < ntiles; tile += gridDim.x * 16) {
        int tb = tile * 16;
        int e = min(tb + r, E - 1);
        int ci = hi[e], ti = wi[e];

        bool ev2 = (tb + r2) < E;
        int dstv = dst[min(tb + r2, E - 1)];

        floatx4 acc[8];
#pragma unroll
        for (int t = 0; t < 8; ++t) acc[t] = (floatx4){0.f,0.f,0.f,0.f};

        // issue ALL cfeat gathers up front (8 x global_load_dwordx4 in flight)
        const float4* cf = (const float4*)(cfeat + (size_t)ci * 128);
        float4 p[8];
#pragma unroll
        for (int s = 0; s < 4; ++s) {
            p[2*s]   = cf[s*8 + g*2];
            p[2*s+1] = cf[s*8 + g*2 + 1];
        }

        // relpose MLP slices: K in [128,256) -> s = 4..7 (covers gather latency)
        float4 cp = ((const float4*)cpose)[ci];
        float4 tp = ((const float4*)tpose)[ti];
        float d0 = cp.x - tp.x, d1 = cp.y - tp.y, d2 = cp.z - tp.z, d3 = cp.w - tp.w;
#pragma unroll
        for (int sp = 0; sp < 4; ++sp) {
            int k0 = sp * 32 + g * 8;
            const float4* w0 = (const float4*)(W_rp + k0);
            const float4* w1 = (const float4*)(W_rp + 128 + k0);
            const float4* w2 = (const float4*)(W_rp + 256 + k0);
            const float4* w3 = (const float4*)(W_rp + 384 + k0);
            const float4* bb = (const float4*)(b_rp + k0);
            float o0,o1,o2,o3,o4,o5,o6,o7;
            {
                float4 a0=w0[0], a1=w1[0], a2=w2[0], a3=w3[0], ab=bb[0];
                o0 = fmaxf(d0*a0.x + d1*a1.x + d2*a2.x + d3*a3.x + ab.x, 0.f);
                o1 = fmaxf(d0*a0.y + d1*a1.y + d2*a2.y + d3*a3.y + ab.y, 0.f);
                o2 = fmaxf(d0*a0.z + d1*a1.z + d2*a2.z + d3*a3.z + ab.z, 0.f);
                o3 = fmaxf(d0*a0.w + d1*a1.w + d2*a2.w + d3*a3.w + ab.w, 0.f);
            }
            {
                float4 a0=w0[1], a1=w1[1], a2=w2[1], a3=w3[1], ab=bb[1];
                o4 = fmaxf(d0*a0.x + d1*a1.x + d2*a2.x + d3*a3.x + ab.x, 0.f);
                o5 = fmaxf(d0*a0.y + d1*a1.y + d2*a2.y + d3*a3.y + ab.y, 0.f);
                o6 = fmaxf(d0*a0.z + d1*a1.z + d2*a2.z + d3*a3.z + ab.z, 0.f);
                o7 = fmaxf(d0*a0.w + d1*a1.w + d2*a2.w + d3*a3.w + ab.w, 0.f);
            }
            bf16x8 aF = { (bf16_t)o0, (bf16_t)o1, (bf16_t)o2, (bf16_t)o3,
                          (bf16_t)o4, (bf16_t)o5, (bf16_t)o6, (bf16_t)o7 };
            int s = 4 + sp;
#pragma unroll
            for (int t = 0; t < 8; ++t) {
                bf16x8 bF = *(const bf16x8*)&sB[((t*8 + s)*64 + lane)*8];
                acc[t] = __builtin_amdgcn_mfma_f32_16x16x32_bf16(aF, bF, acc[t], 0, 0, 0);
            }
        }
        // cfeat slices: K in [0,128) -> s = 0..3, data already in registers
#pragma unroll
        for (int s = 0; s < 4; ++s) {
            float4 v0 = p[2*s], v1 = p[2*s+1];
            bf16x8 aF = { (bf16_t)v0.x, (bf16_t)v0.y, (bf16_t)v0.z, (bf16_t)v0.w,
                          (bf16_t)v1.x, (bf16_t)v1.y, (bf16_t)v1.z, (bf16_t)v1.w };
#pragma unroll
            for (int t = 0; t < 8; ++t) {
                bf16x8 bF = *(const bf16x8*)&sB[((t*8 + s)*64 + lane)*8];
                acc[t] = __builtin_amdgcn_mfma_f32_16x16x32_bf16(aF, bF, acc[t], 0, 0, 0);
            }
        }
        gn_rows(acc, lane, g_ctx, be_ctx, true);

        // restage h into per-wave LDS: row = g*4+rr, col = t*16 + r (conflict-free)
#pragma unroll
        for (int t = 0; t < 8; ++t)
#pragma unroll
            for (int rr = 0; rr < 4; ++rr)
                sH[wave][(g*4 + rr)*136 + t*16 + r] = (bf16_t)acc[t][rr];

        // write-out: 4 lanes per row, plain stores to the precomputed slot
        if (ev2) {
            bf16_t* hp = hbuf + (size_t)dstv * 128 + c2 * 32;
#pragma unroll
            for (int i = 0; i < 4; ++i)
                *(bf16x8*)(hp + i*8) = *(const bf16x8*)&sH[wave][r2*136 + c2*32 + i*8];
        }
    }
}

// ---------------------------------------------------------------------------
// K3 (v3b): barrier-free, per-wave independent (unchanged from round 5).
// ---------------------------------------------------------------------------
__global__ __launch_bounds__(256) void k_out3(
    const float* __restrict__ tfeat, const bf16_t* __restrict__ hbuf,
    const int* __restrict__ off,
    const float* __restrict__ g_n, const float* __restrict__ be_n,
    const float* __restrict__ g_m1, const float* __restrict__ be_m1,
    const float* __restrict__ g_m2, const float* __restrict__ be_m2,
    const bf16_t* __restrict__ swIn, const bf16_t* __restrict__ swC2,
    const bf16_t* __restrict__ swM1, const bf16_t* __restrict__ swM2,
    float* __restrict__ out, int Nt)
{
    __shared__ alignas(16) bf16_t sB[4][2176];   // per-wave [16][136] bf16
    int tid = threadIdx.x, lane = tid & 63, wave = tid >> 6;
    int tb = (blockIdx.x*4 + wave)*16;
    int r = lane & 15, g = lane >> 4;
    int grow = tb + r;
    bool rv = grow < Nt;
    int rclamp = rv ? grow : (Nt - 1);

    // issue ALL tfeat loads up front (covered by the bin gather below)
    const float4* cf = (const float4*)(tfeat + (size_t)rclamp * 128);
    float4 p[8];
#pragma unroll
    for (int s = 0; s < 4; ++s) {
        p[2*s]   = cf[s*8 + g*2];
        p[2*s+1] = cf[s*8 + g*2 + 1];
    }

    // ---- bin gather-sum straight into this lane's A-frag cols {s*32+g*8..+8}
    float sums[32];
#pragma unroll
    for (int i = 0; i < 32; ++i) sums[i] = 0.f;
    int jb = rv ? off[grow] : 0, je = rv ? off[grow+1] : 0;
    for (int jr = jb; jr < je; ++jr) {
        const bf16_t* hp = hbuf + (size_t)jr*128 + g*8;
#pragma unroll
        for (int s = 0; s < 4; ++s) {
            bf16x8 hv = *(const bf16x8*)(hp + s*32);
#pragma unroll
            for (int q = 0; q < 8; ++q) sums[s*8+q] += (float)hv[q];
        }
    }
    // spill Hsum A-frags to per-wave LDS (frees 32 f32 regs; lane-local data)
#pragma unroll
    for (int s = 0; s < 4; ++s) {
        bf16x8 ah = { (bf16_t)sums[s*8+0], (bf16_t)sums[s*8+1],
                      (bf16_t)sums[s*8+2], (bf16_t)sums[s*8+3],
                      (bf16_t)sums[s*8+4], (bf16_t)sums[s*8+5],
                      (bf16_t)sums[s*8+6], (bf16_t)sums[s*8+7] };
        *(bf16x8*)&sB[wave][r*136 + s*32 + g*8] = ah;
    }

    // ---- gemm1: acc = tfeat@W_in + Hsum@W_ctx2  (s-outer; data in regs/LDS)
    floatx4 acc[8];
#pragma unroll
    for (int t = 0; t < 8; ++t) acc[t] = (floatx4){0.f,0.f,0.f,0.f};
#pragma unroll
    for (int s = 0; s < 4; ++s) {
        bf16x8 aH = *(const bf16x8*)&sB[wave][r*136 + s*32 + g*8];
#pragma unroll
        for (int t = 0; t < 8; ++t) {
            bf16x8 bF = *(const bf16x8*)&swC2[((t*4+s)*64 + lane)*8];
            acc[t] = __builtin_amdgcn_mfma_f32_16x16x32_bf16(aH, bF, acc[t], 0, 0, 0);
        }
        float4 v0 = p[2*s], v1 = p[2*s+1];
        bf16x8 aF = { (bf16_t)v0.x, (bf16_t)v0.y, (bf16_t)v0.z, (bf16_t)v0.w,
                      (bf16_t)v1.x, (bf16_t)v1.y, (bf16_t)v1.z, (bf16_t)v1.w };
#pragma unroll
        for (int t = 0; t < 8; ++t) {
            bf16x8 bF = *(const bf16x8*)&swIn[((t*4+s)*64 + lane)*8];
            acc[t] = __builtin_amdgcn_mfma_f32_16x16x32_bf16(aF, bF, acc[t], 0, 0, 0);
        }
    }
    gn_rows(acc, lane, g_n, be_n, true);

    // ---- restage -> gemm2 (W_m1)
#pragma unroll
    for (int t = 0; t < 8; ++t)
#pragma unroll
        for (int rr = 0; rr < 4; ++rr)
            sB[wave][(g*4 + rr)*136 + t*16 + r] = (bf16_t)acc[t][rr];
#pragma unroll
    for (int t = 0; t < 8; ++t) acc[t] = (floatx4){0.f,0.f,0.f,0.f};
#pragma unroll
    for (int s = 0; s < 4; ++s) {
        bf16x8 aF = *(const bf16x8*)&sB[wave][r*136 + s*32 + g*8];
#pragma unroll
        for (int t = 0; t < 8; ++t) {
            bf16x8 bF = *(const bf16x8*)&swM1[((t*4+s)*64 + lane)*8];
            acc[t] = __builtin_amdgcn_mfma_f32_16x16x32_bf16(aF, bF, acc[t], 0, 0, 0);
        }
    }
    gn_rows(acc, lane, g_m1, be_m1, true);

    // ---- restage -> gemm3 (W_m2)
#pragma unroll
    for (int t = 0; t < 8; ++t)
#pragma unroll
        for (int rr = 0; rr < 4; ++rr)
            sB[wave][(g*4 + rr)*136 + t*16 + r] = (bf16_t)acc[t][rr];
#pragma unroll
    for (int t = 0; t < 8; ++t) acc[t] = (floatx4){0.f,0.f,0.f,0.f};
#pragma unroll
    for (int s = 0; s < 4; ++s) {
        bf16x8 aF = *(const bf16x8*)&sB[wave][r*136 + s*32 + g*8];
#pragma unroll
        for (int t = 0; t < 8; ++t) {
            bf16x8 bF = *(const bf16x8*)&swM2[((t*4+s)*64 + lane)*8];
            acc[t] = __builtin_amdgcn_mfma_f32_16x16x32_bf16(aF, bF, acc[t], 0, 0, 0);
        }
    }
    gn_rows(acc, lane, g_m2, be_m2, false);

    // ---- epilogue: +identity, relu, direct C-layout stores (64B segments)
#pragma unroll
    for (int t = 0; t < 8; ++t) {
        int n = t*16 + r;
#pragma unroll
        for (int rr = 0; rr < 4; ++rr) {
            int row = tb + g*4 + rr;
            if (row < Nt) {
                float v = acc[t][rr] + tfeat[(size_t)row*128 + n];
                out[(size_t)row*128 + n] = fmaxf(v, 0.f);
            }
        }
    }
}

// ===========================================================================
// FALLBACK PATH (previous kernels, used only if workspace is too small for
// the binned h buffer).
// ===========================================================================
__global__ __launch_bounds__(256) void k_gemm_in(
    const float* __restrict__ tfeat, const bf16_t* __restrict__ swW,
    float* __restrict__ tf, int Nt)
{
    __shared__ alignas(16) bf16_t sA[4][2048];
    int tid = threadIdx.x, lane = tid & 63, wave = tid >> 6;

    int tb = (blockIdx.x * 4 + wave) * 16;
    int r = lane >> 2, cb = (lane & 3) * 32;
    int grow = tb + r;
    bool rv = grow < Nt;
    const float4* src = (const float4*)(tfeat + (size_t)(rv ? grow : 0) * 128 + cb);
#pragma unroll
    for (int i = 0; i < 8; ++i) {
        float4 v = rv ? src[i] : make_float4(0.f,0.f,0.f,0.f);
        int k = cb + 4*i;
        int s = k >> 5, q = (k >> 3) & 3, j = k & 7;
        bf16x4 pk = { (bf16_t)v.x, (bf16_t)v.y, (bf16_t)v.z, (bf16_t)v.w };
        *(bf16x4*)&sA[wave][(s*64 + q*16 + r)*8 + j] = pk;
    }
    __syncthreads();
    int m = lane & 15, g = lane >> 4;
    bf16x8 aF[4];
#pragma unroll
    for (int s = 0; s < 4; ++s) aF[s] = *(const bf16x8*)&sA[wave][(s*64 + lane)*8];
#pragma unroll
    for (int t = 0; t < 8; ++t) {
        floatx4 a = {0.f,0.f,0.f,0.f};
#pragma unroll
        for (int s = 0; s < 4; ++s) {
            bf16x8 bF = *(const bf16x8*)&swW[((t*4+s)*64 + lane)*8];
            a = __builtin_amdgcn_mfma_f32_16x16x32_bf16(aF[s], bF, a, 0, 0, 0);
        }
#pragma unroll
        for (int rr = 0; rr < 4; ++rr) {
            int row = tb + g*4 + rr;
            if (row < Nt) tf[(size_t)row*128 + t*16 + m] = a[rr];
        }
    }
}

__global__ __launch_bounds__(256) void k_edge_old(
    const float* __restrict__ cfeat, const float* __restrict__ cpose,
    const float* __restrict__ tpose, const int* __restrict__ hi,
    const int* __restrict__ wi, const float* __restrict__ W_rp,
    const float* __restrict__ b_rp, const float* __restrict__ g_ctx,
    const float* __restrict__ be_ctx, const bf16_t* __restrict__ swC1,
    const bf16_t* __restrict__ swC2, float* __restrict__ tf, int E)
{
    __shared__ alignas(16) bf16_t sA[4][4096];
    int tid = threadIdx.x, lane = tid & 63, wave = tid >> 6;

    int tb = (blockIdx.x * 4 + wave) * 16;
    int r = lane >> 2, cb = (lane & 3) * 32;
    int e = min(tb + r, E - 1);
    int ci = hi[e], ti = wi[e];
    const float4* src = (const float4*)(cfeat + (size_t)ci * 128 + cb);
#pragma unroll
    for (int i = 0; i < 8; ++i) {
        float4 v = src[i];
        int k = cb + 4*i;
        int s = k >> 5, q = (k >> 3) & 3, j = k & 7;
        bf16x4 pk = { (bf16_t)v.x, (bf16_t)v.y, (bf16_t)v.z, (bf16_t)v.w };
        *(bf16x4*)&sA[wave][(s*64 + q*16 + r)*8 + j] = pk;
    }
    float4 cp = ((const float4*)cpose)[ci];
    float4 tp = ((const float4*)tpose)[ti];
    float d0 = cp.x - tp.x, d1 = cp.y - tp.y, d2 = cp.z - tp.z, d3 = cp.w - tp.w;
#pragma unroll
    for (int i = 0; i < 8; ++i) {
        int cc = cb + 4*i;
        float4 w0 = *(const float4*)(W_rp + cc);
        float4 w1 = *(const float4*)(W_rp + 128 + cc);
        float4 w2 = *(const float4*)(W_rp + 256 + cc);
        float4 w3 = *(const float4*)(W_rp + 384 + cc);
        float4 bb = *(const float4*)(b_rp + cc);
        float o0 = fmaxf(d0*w0.x + d1*w1.x + d2*w2.x + d3*w3.x + bb.x, 0.f);
        float o1 = fmaxf(d0*w0.y + d1*w1.y + d2*w2.y + d3*w3.y + bb.y, 0.f);
        float o2 = fmaxf(d0*w0.z + d1*w1.z + d2*w2.z + d3*w3.z + bb.z, 0.f);
        float o3 = fmaxf(d0*w0.w + d1*w1.w + d2*w2.w + d3*w3.w + bb.w, 0.f);
        int k = 128 + cc;
        int s = k >> 5, q = (k >> 3) & 3, j = k & 7;
        bf16x4 pk = { (bf16_t)o0, (bf16_t)o1, (bf16_t)o2, (bf16_t)o3 };
        *(bf16x4*)&sA[wave][(s*64 + q*16 + r)*8 + j] = pk;
    }
    __syncthreads();

    int m = lane & 15, g = lane >> 4;
    bf16x8 aF[8];
#pragma unroll
    for (int s = 0; s < 8; ++s) aF[s] = *(const bf16x8*)&sA[wave][(s*64 + lane)*8];
    floatx4 acc[8];
#pragma unroll
    for (int t = 0; t < 8; ++t) {
        floatx4 a = {0.f,0.f,0.f,0.f};
#pragma unroll
        for (int s = 0; s < 8; ++s) {
            bf16x8 bF = *(const bf16x8*)&swC1[(size_t)((t*8+s)*64 + lane)*8];
            a = __builtin_amdgcn_mfma_f32_16x16x32_bf16(aF[s], bF, a, 0, 0, 0);
        }
        acc[t] = a;
    }
    gn_rows(acc, lane, g_ctx, be_ctx, true);
    __syncthreads();
#pragma unroll
    for (int t = 0; t < 8; ++t) {
        int n = t*16 + m;
        int s = n >> 5, q = (n >> 3) & 3, j = n & 7;
#pragma unroll
        for (int rr = 0; rr < 4; ++rr)
            sA[wave][(s*64 + q*16 + (g*4+rr))*8 + j] = (bf16_t)acc[t][rr];
    }
    __syncthreads();
    bf16x8 aF2[4];
#pragma unroll
    for (int s = 0; s < 4; ++s) aF2[s] = *(const bf16x8*)&sA[wave][(s*64 + lane)*8];
    int dstrow[4]; bool vald[4];
#pragma unroll
    for (int rr = 0; rr < 4; ++rr) {
        int ee = tb + g*4 + rr;
        vald[rr] = ee < E;
        dstrow[rr] = vald[rr] ? wi[ee] : 0;
    }
#pragma unroll
    for (int t = 0; t < 8; ++t) {
        floatx4 a = {0.f,0.f,0.f,0.f};
#pragma unroll
        for (int s = 0; s < 4; ++s) {
            bf16x8 bF = *(const bf16x8*)&swC2[((t*4+s)*64 + lane)*8];
            a = __builtin_amdgcn_mfma_f32_16x16x32_bf16(aF2[s], bF, a, 0, 0, 0);
        }
#pragma unroll
        for (int rr = 0; rr < 4; ++rr) {
            if (vald[rr])
                atomicAdd(&tf[(size_t)dstrow[rr]*128 + t*16 + m], a[rr]);
        }
    }
}

__global__ __launch_bounds__(256) void k_out_old(
    const float* __restrict__ tf, const float* __restrict__ identity,
    const float* __restrict__ g_n, const float* __restrict__ be_n,
    const float* __restrict__ g_m1, const float* __restrict__ be_m1,
    const float* __restrict__ g_m2, const float* __restrict__ be_m2,
    const bf16_t* __restrict__ swM1, const bf16_t* __restrict__ swM2,
    float* __restrict__ out, int Nt)
{
    __shared__ alignas(16) bf16_t sA[4][2048];
    int tid = threadIdx.x, lane = tid & 63, wave = tid >> 6;

    int tb = (blockIdx.x*4 + wave)*16;
    int r = lane >> 2, cb = (lane & 3)*32;
    int grow = tb + r;
    bool rv = grow < Nt;
    const float4* src = (const float4*)(tf + (size_t)(rv ? grow : 0)*128 + cb);
    float vals[32];
    float ls = 0.f, lq = 0.f;
#pragma unroll
    for (int i = 0; i < 8; ++i) {
        float4 v = rv ? src[i] : make_float4(0.f,0.f,0.f,0.f);
        vals[4*i+0]=v.x; vals[4*i+1]=v.y; vals[4*i+2]=v.z; vals[4*i+3]=v.w;
        ls += v.x+v.y+v.z+v.w;
        lq += v.x*v.x+v.y*v.y+v.z*v.z+v.w*v.w;
    }
    ls += __shfl_xor(ls,1); lq += __shfl_xor(lq,1);
    ls += __shfl_xor(ls,2); lq += __shfl_xor(lq,2);
    float mean = ls*(1.f/128.f);
    float inv = rsqrtf(lq*(1.f/128.f) - mean*mean + EPSF);
#pragma unroll
    for (int i = 0; i < 8; ++i) {
        int cc = cb + 4*i;
        float4 ga = *(const float4*)(g_n + cc);
        float4 be = *(const float4*)(be_n + cc);
        float o0 = fmaxf((vals[4*i+0]-mean)*inv*ga.x + be.x, 0.f);
        float o1 = fmaxf((vals[4*i+1]-mean)*inv*ga.y + be.y, 0.f);
        float o2 = fmaxf((vals[4*i+2]-mean)*inv*ga.z + be.z, 0.f);
        float o3 = fmaxf((vals[4*i+3]-mean)*inv*ga.w + be.w, 0.f);
        int s = cc >> 5, q = (cc >> 3) & 3, j = cc & 7;
        bf16x4 pk = { (bf16_t)o0, (bf16_t)o1, (bf16_t)o2, (bf16_t)o3 };
        *(bf16x4*)&sA[wave][(s*64 + q*16 + r)*8 + j] = pk;
    }
    __syncthreads();
    int m = lane & 15, g = lane >> 4;
    bf16x8 aF[4];
#pragma unroll
    for (int s = 0; s < 4; ++s) aF[s] = *(const bf16x8*)&sA[wave][(s*64 + lane)*8];
    floatx4 acc[8];
#pragma unroll
    for (int t = 0; t < 8; ++t) {
        floatx4 a = {0.f,0.f,0.f,0.f};
#pragma unroll
        for (int s = 0; s < 4; ++s) {
            bf16x8 bF = *(const bf16x8*)&swM1[((t*4+s)*64 + lane)*8];
            a = __builtin_amdgcn_mfma_f32_16x16x32_bf16(aF[s], bF, a, 0, 0, 0);
        }
        acc[t] = a;
    }
    gn_rows(acc, lane, g_m1, be_m1, true);
    __syncthreads();
#pragma unroll
    for (int t = 0; t < 8; ++t) {
        int n = t*16 + m;
        int s = n >> 5, q = (n >> 3) & 3, j = n & 7;
#pragma unroll
        for (int rr = 0; rr < 4; ++rr)
            sA[wave][(s*64 + q*16 + (g*4+rr))*8 + j] = (bf16_t)acc[t][rr];
    }
    __syncthreads();
#pragma unroll
    for (int s = 0; s < 4; ++s) aF[s] = *(const bf16x8*)&sA[wave][(s*64 + lane)*8];
#pragma unroll
    for (int t = 0; t < 8; ++t) {
        floatx4 a = {0.f,0.f,0.f,0.f};
#pragma unroll
        for (int s = 0; s < 4; ++s) {
            bf16x8 bF = *(const bf16x8*)&swM2[((t*4+s)*64 + lane)*8];
            a = __builtin_amdgcn_mfma_f32_16x16x32_bf16(aF[s], bF, a, 0, 0, 0);
        }
        acc[t] = a;
    }
    gn_rows(acc, lane, g_m2, be_m2, false);
#pragma unroll
    for (int t = 0; t < 8; ++t) {
        int n = t*16 + m;
#pragma unroll
        for (int rr = 0; rr < 4; ++rr) {
            int row = tb + g*4 + rr;
            if (row < Nt) {
                float v = acc[t][rr] + identity[(size_t)row*128 + n];
                out[(size_t)row*128 + n] = fmaxf(v, 0.f);
            }
        }
    }
}

// ---------------------------------------------------------------------------
extern "C" void kernel_launch(void* const* d_in, const int* in_sizes, int n_in,
                              void* d_out, int out_size, void* d_ws, size_t ws_size,
                              hipStream_t stream)
{
    const float* cfeat  = (const float*)d_in[0];
    const float* tfeat  = (const float*)d_in[1];
    const float* cpose  = (const float*)d_in[2];
    const float* tpose  = (const float*)d_in[3];
    const int*   hi     = (const int*)d_in[4];
    const int*   wi     = (const int*)d_in[5];
    const float* W_in   = (const float*)d_in[6];
    const float* W_rp   = (const float*)d_in[7];
    const float* b_rp   = (const float*)d_in[8];
    const float* W_ctx1 = (const float*)d_in[9];
    const float* g_ctx  = (const float*)d_in[10];
    const float* be_ctx = (const float*)d_in[11];
    const float* W_ctx2 = (const float*)d_in[12];
    const float* g_n    = (const float*)d_in[13];
    const float* be_n   = (const float*)d_in[14];
    const float* W_m1   = (const float*)d_in[15];
    const float* g_m1   = (const float*)d_in[16];
    const float* be_m1  = (const float*)d_in[17];
    const float* W_m2   = (const float*)d_in[18];
    const float* g_m2   = (const float*)d_in[19];
    const float* be_m2  = (const float*)d_in[20];

    int Nt = in_sizes[1] / 128;
    int E  = in_sizes[4];
    float* outp = (float*)d_out;

    // new-path workspace layout
    char* base = (char*)d_ws;
    size_t o = 98304 * sizeof(bf16_t);                 // sw @ 0
    o = (o + 255) & ~(size_t)255;
    size_t o_cnt = o; o += (size_t)Nt * 4;             // wi histogram
    o = (o + 255) & ~(size_t)255;
    size_t o_off = o; o += ((size_t)Nt + 1) * 4;       // wi offsets
    o = (o + 255) & ~(size_t)255;
    size_t o_cur = o; o += (size_t)Nt * 4;             // wi slot cursors
    o = (o + 255) & ~(size_t)255;
    size_t o_bsum = o; o += 1024 * 4;                  // scan block sums
    o = (o + 255) & ~(size_t)255;
    size_t o_dst = o; o += (size_t)E * 4;              // per-edge slot
    o = (o + 255) & ~(size_t)255;
    size_t o_h = o; o += (size_t)E * 128 * sizeof(bf16_t);

    int NB = (Nt + 4095) / 4096;                       // scan blocks (<=1024)

    if (ws_size >= o && NB <= 1024) {
        bf16_t* sw    = (bf16_t*)base;
        int*    cnt   = (int*)(base + o_cnt);
        int*    off   = (int*)(base + o_off);
        int*    cur   = (int*)(base + o_cur);
        int*    bsum  = (int*)(base + o_bsum);
        int*    dst   = (int*)(base + o_dst);
        bf16_t* hbuf  = (bf16_t*)(base + o_h);
        bf16_t* swIn = sw;
        bf16_t* swC1 = sw + 16384;
        bf16_t* swC2 = sw + 49152;
        bf16_t* swM1 = sw + 65536;
        bf16_t* swM2 = sw + 81920;

        hipMemsetAsync(cnt, 0, (size_t)Nt * 4, stream);
        hipMemsetAsync(cur, 0, (size_t)Nt * 4, stream);
        k_prep<<<384, 256, 0, stream>>>(W_in, W_ctx1, W_ctx2, W_m1, W_m2, sw);
        k_count<<<(E + 255) / 256, 256, 0, stream>>>(wi, cnt, E);
        k_scanA<<<NB, 1024, 0, stream>>>(cnt, off, bsum, Nt);
        k_scanB<<<1, 1024, 0, stream>>>(bsum, off, NB, Nt);
        k_scanC<<<(Nt + 255) / 256, 256, 0, stream>>>(off, bsum, Nt);
        k_slots<<<(E + 255) / 256, 256, 0, stream>>>(wi, off, cur, dst, E);
        int ntiles = (E + 15) / 16;
        int nb9 = (ntiles + 15) / 16; if (nb9 > 256) nb9 = 256;
        k_edge9<<<nb9, 1024, 0, stream>>>(cfeat, cpose, tpose, hi, wi,
                                          dst, W_rp, b_rp, g_ctx, be_ctx,
                                          swC1, hbuf, E);
        k_out3<<<(Nt + 63) / 64, 256, 0, stream>>>(tfeat, hbuf, off,
                                                   g_n, be_n, g_m1, be_m1,
                                                   g_m2, be_m2,
                                                   swIn, swC2, swM1, swM2,
                                                   outp, Nt);
    } else {
        // fallback: previous atomic-scatter path
        float*  tf = (float*)d_ws;                                   // [Nt,128] f32
        bf16_t* sw = (bf16_t*)((char*)d_ws + (size_t)Nt * 128 * sizeof(float));
        bf16_t* swIn = sw;
        bf16_t* swC1 = sw + 16384;
        bf16_t* swC2 = sw + 49152;
        bf16_t* swM1 = sw + 65536;
        bf16_t* swM2 = sw + 81920;

        k_prep<<<384, 256, 0, stream>>>(W_in, W_ctx1, W_ctx2, W_m1, W_m2, sw);
        k_gemm_in<<<(Nt + 63) / 64, 256, 0, stream>>>(tfeat, swIn, tf, Nt);
        k_edge_old<<<(E + 63) / 64, 256, 0, stream>>>(cfeat, cpose, tpose, hi, wi,
                                                      W_rp, b_rp, g_ctx, be_ctx,
                                                      swC1, swC2, tf, E);
        k_out_old<<<(Nt + 63) / 64, 256, 0, stream>>>(tf, tfeat, g_n, be_n,
                                                      g_m1, be_m1, g_m2, be_m2,
                                                      swM1, swM2, outp, Nt);
    }
}

// Round 11
// 461.750 us; speedup vs baseline: 2.5310x; 2.5310x over previous
//
#include <hip/hip_runtime.h>

typedef __bf16 bf16_t;
typedef bf16_t bf16x4 __attribute__((ext_vector_type(4)));
typedef bf16_t bf16x8 __attribute__((ext_vector_type(8)));
typedef float floatx4 __attribute__((ext_vector_type(4)));

#define EPSF 1e-5f
#define DEV static __device__ __forceinline__

// ---------------------------------------------------------------------------
// K0: swizzle weight matrices (f32 [K][128]) into B-fragment order, bf16.
// sw[((t*nK + s)*64 + l)*8 + j] = W[(s*32 + (l>>4)*8 + j)*128 + (t*16 + (l&15))]
// Layout ranges (bf16 elems): W_in@0(16384), W_ctx1@16384(32768),
// W_ctx2@49152(16384), W_m1@65536(16384), W_m2@81920(16384). Total 98304.
// ---------------------------------------------------------------------------
__global__ __launch_bounds__(256) void k_prep(
    const float* __restrict__ W_in, const float* __restrict__ W_ctx1,
    const float* __restrict__ W_ctx2, const float* __restrict__ W_m1,
    const float* __restrict__ W_m2, bf16_t* __restrict__ sw)
{
    int idx = blockIdx.x * 256 + threadIdx.x;   // grid sized to exactly 98304
    const float* W; int base, ks;
    if (idx < 16384)      { W = W_in;   base = 0;     ks = 2; }
    else if (idx < 49152) { W = W_ctx1; base = 16384; ks = 3; }
    else if (idx < 65536) { W = W_ctx2; base = 49152; ks = 2; }
    else if (idx < 81920) { W = W_m1;   base = 65536; ks = 2; }
    else                  { W = W_m2;   base = 81920; ks = 2; }
    int local = idx - base;
    int j = local & 7, l = (local >> 3) & 63, rest = local >> 9;
    int s = rest & ((1 << ks) - 1), t = rest >> ks;
    int k = s * 32 + (l >> 4) * 8 + j;
    int n = t * 16 + (l & 15);
    sw[idx] = (bf16_t)W[k * 128 + n];
}

// GroupNorm over 128 channels per row, operating on MFMA C-layout accumulators.
// acc[t][rr] holds element (row = (lane>>4)*4+rr, col = t*16 + (lane&15)).
DEV void gn_rows(floatx4* acc, int lane, const float* __restrict__ gamma,
                 const float* __restrict__ beta, bool do_relu)
{
    int m = lane & 15;
    float s1[4] = {0.f,0.f,0.f,0.f}, s2[4] = {0.f,0.f,0.f,0.f};
#pragma unroll
    for (int t = 0; t < 8; ++t)
#pragma unroll
        for (int rr = 0; rr < 4; ++rr) { float v = acc[t][rr]; s1[rr] += v; s2[rr] += v*v; }
#pragma unroll
    for (int mask = 1; mask <= 8; mask <<= 1)
#pragma unroll
        for (int rr = 0; rr < 4; ++rr) {
            s1[rr] += __shfl_xor(s1[rr], mask);
            s2[rr] += __shfl_xor(s2[rr], mask);
        }
    float mean[4], inv[4];
#pragma unroll
    for (int rr = 0; rr < 4; ++rr) {
        mean[rr] = s1[rr] * (1.f/128.f);
        float var = s2[rr] * (1.f/128.f) - mean[rr]*mean[rr];
        inv[rr] = rsqrtf(var + EPSF);
    }
#pragma unroll
    for (int t = 0; t < 8; ++t) {
        int n = t*16 + m;
        float ga = gamma[n], be = beta[n];
#pragma unroll
        for (int rr = 0; rr < 4; ++rr) {
            float v = (acc[t][rr] - mean[rr]) * inv[rr] * ga + be;
            acc[t][rr] = do_relu ? fmaxf(v, 0.f) : v;
        }
    }
}

// ---------------------------------------------------------------------------
// Binning: histogram of wi, HIERARCHICAL exclusive scan -> off[Nt+1], then a
// massive-TLP slot-assignment kernel writing dst[e].
// ---------------------------------------------------------------------------
__global__ __launch_bounds__(256) void k_count(const int* __restrict__ idxs,
                                               int* __restrict__ cnt, int E)
{
    int e = blockIdx.x * 256 + threadIdx.x;
    if (e < E) atomicAdd(&cnt[idxs[e]], 1);
}

// scan stage A: each block exclusive-scans its 4096 elements, emits block sum
__global__ __launch_bounds__(1024) void k_scanA(const int* __restrict__ cnt,
                                                int* __restrict__ off,
                                                int* __restrict__ bsum, int N)
{
    __shared__ int wsum[16];
    int tid = threadIdx.x, lane = tid & 63, wid = tid >> 6;
    int i0 = blockIdx.x * 4096 + tid * 4;
    int v0 = 0, v1 = 0, v2 = 0, v3 = 0;
    if (i0 + 3 < N) {
        int4 v = *(const int4*)(cnt + i0);
        v0 = v.x; v1 = v.y; v2 = v.z; v3 = v.w;
    } else {
        if (i0     < N) v0 = cnt[i0];
        if (i0 + 1 < N) v1 = cnt[i0+1];
        if (i0 + 2 < N) v2 = cnt[i0+2];
        if (i0 + 3 < N) v3 = cnt[i0+3];
    }
    int tot = v0 + v1 + v2 + v3;
    int x = tot;
#pragma unroll
    for (int d = 1; d < 64; d <<= 1) {
        int y = __shfl_up(x, d);
        if (lane >= d) x += y;
    }
    if (lane == 63) wsum[wid] = x;
    __syncthreads();
    if (wid == 0) {
        int wv = (lane < 16) ? wsum[lane] : 0;
#pragma unroll
        for (int d = 1; d < 16; d <<= 1) {
            int y = __shfl_up(wv, d);
            if (lane >= d) wv += y;
        }
        if (lane < 16) wsum[lane] = wv;
    }
    __syncthreads();
    int ebase = ((wid > 0) ? wsum[wid-1] : 0) + (x - tot);
    if (i0 + 3 < N) {
        *(int4*)(off + i0) = make_int4(ebase, ebase+v0, ebase+v0+v1, ebase+v0+v1+v2);
    } else {
        if (i0     < N) off[i0]   = ebase;
        if (i0 + 1 < N) off[i0+1] = ebase + v0;
        if (i0 + 2 < N) off[i0+2] = ebase + v0 + v1;
        if (i0 + 3 < N) off[i0+3] = ebase + v0 + v1 + v2;
    }
    if (tid == 0) bsum[blockIdx.x] = wsum[15];
}

// scan stage B: exclusive-scan the (<=1024) block sums in place; off[N] = total
__global__ __launch_bounds__(1024) void k_scanB(int* __restrict__ bsum,
                                                int* __restrict__ off,
                                                int NB, int N)
{
    __shared__ int wsum[16];
    int tid = threadIdx.x, lane = tid & 63, wid = tid >> 6;
    int v = (tid < NB) ? bsum[tid] : 0;
    int x = v;
#pragma unroll
    for (int d = 1; d < 64; d <<= 1) {
        int y = __shfl_up(x, d);
        if (lane >= d) x += y;
    }
    if (lane == 63) wsum[wid] = x;
    __syncthreads();
    if (wid == 0) {
        int wv = (lane < 16) ? wsum[lane] : 0;
#pragma unroll
        for (int d = 1; d < 16; d <<= 1) {
            int y = __shfl_up(wv, d);
            if (lane >= d) wv += y;
        }
        if (lane < 16) wsum[lane] = wv;
    }
    __syncthreads();
    int excl = ((wid > 0) ? wsum[wid-1] : 0) + (x - v);
    if (tid < NB) bsum[tid] = excl;
    if (tid == 0) off[N] = wsum[15];
}

// scan stage C: add block carries
__global__ __launch_bounds__(256) void k_scanC(int* __restrict__ off,
                                               const int* __restrict__ bsum, int N)
{
    int i = blockIdx.x * 256 + threadIdx.x;
    if (i < N) off[i] += bsum[i >> 12];
}

// slot assignment: one atomic per THREAD at full occupancy -> latency hidden
__global__ __launch_bounds__(256) void k_slots(const int* __restrict__ wi,
                                               const int* __restrict__ off,
                                               int* __restrict__ cur,
                                               int* __restrict__ dst, int E)
{
    int e = blockIdx.x * 256 + threadIdx.x;
    if (e < E) {
        int w = wi[e];
        dst[e] = off[w] + atomicAdd(&cur[w], 1);
    }
}

// ---------------------------------------------------------------------------
// K2 (v10): round-8 verified 256-thread body (474us total, k_edge 190us) with
// ONE bounded change: the cfeat K-half of swC1 (s=0..3, 32 KB) is staged once
// per block into LDS (one startup barrier; per-wave independence preserved).
// 32 of the 64 per-wave B-reads become ds_read_b128 instead of an L1-thrashed
// L2 chain. LDS 17.4 -> 50 KB (3 blocks/CU >= measured 2.5). Block shape and
// register structure identical to the passing r8 build (no spill risk; the
// r9/r10 1024-thread vehicle spilled at a compiler-chosen 64-VGPR budget that
// __launch_bounds__ could not raise).
// ---------------------------------------------------------------------------
__global__ __launch_bounds__(256) void k_edge10(
    const float* __restrict__ cfeat, const float* __restrict__ cpose,
    const float* __restrict__ tpose, const int* __restrict__ hi,
    const int* __restrict__ wi, const int* __restrict__ dst,
    const float* __restrict__ W_rp,
    const float* __restrict__ b_rp, const float* __restrict__ g_ctx,
    const float* __restrict__ be_ctx, const bf16_t* __restrict__ swC1,
    bf16_t* __restrict__ hbuf, int E)
{
    __shared__ alignas(16) bf16_t sH[4][2176];   // per-wave [16][136] bf16
    __shared__ alignas(16) bf16_t sBc[16384];    // swC1 K-half (s=0..3), 32 KB
    int tid = threadIdx.x, lane = tid & 63, wave = tid >> 6;
    int tb = (blockIdx.x * 4 + wave) * 16;
    int r = lane & 15, g = lane >> 4;

    // cooperative stage of the s<4 half of swC1 into LDS.
    // LDS unit u (bf16x8) <- global unit (u>>8)*512 + (u&255):
    // per t-block (512 units) take the first 256 units (s=0..3).
    {
        const bf16x8* gsrc = (const bf16x8*)swC1;
        bf16x8* ldst = (bf16x8*)sBc;
#pragma unroll
        for (int i = 0; i < 8; ++i) {
            int u = i * 256 + tid;
            ldst[u] = gsrc[(u >> 8) * 512 + (u & 255)];
        }
    }
    __syncthreads();

    int e = min(tb + r, E - 1);
    int ci = hi[e], ti = wi[e];

    // plain load of this row group's destination slot (no atomic in this kernel)
    int r2 = lane >> 2, c2 = lane & 3;
    bool ev2 = (tb + r2) < E;
    int dstv = dst[min(tb + r2, E - 1)];

    floatx4 acc[8];
#pragma unroll
    for (int t = 0; t < 8; ++t) acc[t] = (floatx4){0.f,0.f,0.f,0.f};

    // issue ALL cfeat gathers up front (8 x global_load_dwordx4 in flight)
    const float4* cf = (const float4*)(cfeat + (size_t)ci * 128);
    float4 p[8];
#pragma unroll
    for (int s = 0; s < 4; ++s) {
        p[2*s]   = cf[s*8 + g*2];
        p[2*s+1] = cf[s*8 + g*2 + 1];
    }

    // relpose MLP slices: K in [128,256) -> s = 4..7 (B streamed from L2;
    // compute covers the cfeat gather latency)
    float4 cp = ((const float4*)cpose)[ci];
    float4 tp = ((const float4*)tpose)[ti];
    float d0 = cp.x - tp.x, d1 = cp.y - tp.y, d2 = cp.z - tp.z, d3 = cp.w - tp.w;
#pragma unroll
    for (int sp = 0; sp < 4; ++sp) {
        int k0 = sp * 32 + g * 8;
        const float4* w0 = (const float4*)(W_rp + k0);
        const float4* w1 = (const float4*)(W_rp + 128 + k0);
        const float4* w2 = (const float4*)(W_rp + 256 + k0);
        const float4* w3 = (const float4*)(W_rp + 384 + k0);
        const float4* bb = (const float4*)(b_rp + k0);
        float o0,o1,o2,o3,o4,o5,o6,o7;
        {
            float4 a0=w0[0], a1=w1[0], a2=w2[0], a3=w3[0], ab=bb[0];
            o0 = fmaxf(d0*a0.x + d1*a1.x + d2*a2.x + d3*a3.x + ab.x, 0.f);
            o1 = fmaxf(d0*a0.y + d1*a1.y + d2*a2.y + d3*a3.y + ab.y, 0.f);
            o2 = fmaxf(d0*a0.z + d1*a1.z + d2*a2.z + d3*a3.z + ab.z, 0.f);
            o3 = fmaxf(d0*a0.w + d1*a1.w + d2*a2.w + d3*a3.w + ab.w, 0.f);
        }
        {
            float4 a0=w0[1], a1=w1[1], a2=w2[1], a3=w3[1], ab=bb[1];
            o4 = fmaxf(d0*a0.x + d1*a1.x + d2*a2.x + d3*a3.x + ab.x, 0.f);
            o5 = fmaxf(d0*a0.y + d1*a1.y + d2*a2.y + d3*a3.y + ab.y, 0.f);
            o6 = fmaxf(d0*a0.z + d1*a1.z + d2*a2.z + d3*a3.z + ab.z, 0.f);
            o7 = fmaxf(d0*a0.w + d1*a1.w + d2*a2.w + d3*a3.w + ab.w, 0.f);
        }
        bf16x8 aF = { (bf16_t)o0, (bf16_t)o1, (bf16_t)o2, (bf16_t)o3,
                      (bf16_t)o4, (bf16_t)o5, (bf16_t)o6, (bf16_t)o7 };
        int s = 4 + sp;
#pragma unroll
        for (int t = 0; t < 8; ++t) {
            bf16x8 bF = *(const bf16x8*)&swC1[(size_t)((t*8 + s)*64 + lane)*8];
            acc[t] = __builtin_amdgcn_mfma_f32_16x16x32_bf16(aF, bF, acc[t], 0, 0, 0);
        }
    }
    // cfeat slices: K in [0,128) -> s = 0..3, A in registers, B from LDS
#pragma unroll
    for (int s = 0; s < 4; ++s) {
        float4 v0 = p[2*s], v1 = p[2*s+1];
        bf16x8 aF = { (bf16_t)v0.x, (bf16_t)v0.y, (bf16_t)v0.z, (bf16_t)v0.w,
                      (bf16_t)v1.x, (bf16_t)v1.y, (bf16_t)v1.z, (bf16_t)v1.w };
#pragma unroll
        for (int t = 0; t < 8; ++t) {
            bf16x8 bF = *(const bf16x8*)&sBc[(size_t)(t*2048) + (s*64 + lane)*8];
            acc[t] = __builtin_amdgcn_mfma_f32_16x16x32_bf16(aF, bF, acc[t], 0, 0, 0);
        }
    }
    gn_rows(acc, lane, g_ctx, be_ctx, true);

    // restage h into per-wave LDS: row = g*4+rr, col = t*16 + r  (conflict-free)
#pragma unroll
    for (int t = 0; t < 8; ++t)
#pragma unroll
        for (int rr = 0; rr < 4; ++rr)
            sH[wave][(g*4 + rr)*136 + t*16 + r] = (bf16_t)acc[t][rr];

    // write-out: 4 lanes per row, plain stores to the precomputed slot
    if (ev2) {
        bf16_t* hp = hbuf + (size_t)dstv * 128 + c2 * 32;
#pragma unroll
        for (int i = 0; i < 4; ++i)
            *(bf16x8*)(hp + i*8) = *(const bf16x8*)&sH[wave][r2*136 + c2*32 + i*8];
    }
}

// ---------------------------------------------------------------------------
// K3 (v3b): barrier-free, per-wave independent (unchanged from round 5/8).
// ---------------------------------------------------------------------------
__global__ __launch_bounds__(256) void k_out3(
    const float* __restrict__ tfeat, const bf16_t* __restrict__ hbuf,
    const int* __restrict__ off,
    const float* __restrict__ g_n, const float* __restrict__ be_n,
    const float* __restrict__ g_m1, const float* __restrict__ be_m1,
    const float* __restrict__ g_m2, const float* __restrict__ be_m2,
    const bf16_t* __restrict__ swIn, const bf16_t* __restrict__ swC2,
    const bf16_t* __restrict__ swM1, const bf16_t* __restrict__ swM2,
    float* __restrict__ out, int Nt)
{
    __shared__ alignas(16) bf16_t sB[4][2176];   // per-wave [16][136] bf16
    int tid = threadIdx.x, lane = tid & 63, wave = tid >> 6;
    int tb = (blockIdx.x*4 + wave)*16;
    int r = lane & 15, g = lane >> 4;
    int grow = tb + r;
    bool rv = grow < Nt;
    int rclamp = rv ? grow : (Nt - 1);

    // issue ALL tfeat loads up front (covered by the bin gather below)
    const float4* cf = (const float4*)(tfeat + (size_t)rclamp * 128);
    float4 p[8];
#pragma unroll
    for (int s = 0; s < 4; ++s) {
        p[2*s]   = cf[s*8 + g*2];
        p[2*s+1] = cf[s*8 + g*2 + 1];
    }

    // ---- bin gather-sum straight into this lane's A-frag cols {s*32+g*8..+8}
    float sums[32];
#pragma unroll
    for (int i = 0; i < 32; ++i) sums[i] = 0.f;
    int jb = rv ? off[grow] : 0, je = rv ? off[grow+1] : 0;
    for (int jr = jb; jr < je; ++jr) {
        const bf16_t* hp = hbuf + (size_t)jr*128 + g*8;
#pragma unroll
        for (int s = 0; s < 4; ++s) {
            bf16x8 hv = *(const bf16x8*)(hp + s*32);
#pragma unroll
            for (int q = 0; q < 8; ++q) sums[s*8+q] += (float)hv[q];
        }
    }
    // spill Hsum A-frags to per-wave LDS (frees 32 f32 regs; lane-local data)
#pragma unroll
    for (int s = 0; s < 4; ++s) {
        bf16x8 ah = { (bf16_t)sums[s*8+0], (bf16_t)sums[s*8+1],
                      (bf16_t)sums[s*8+2], (bf16_t)sums[s*8+3],
                      (bf16_t)sums[s*8+4], (bf16_t)sums[s*8+5],
                      (bf16_t)sums[s*8+6], (bf16_t)sums[s*8+7] };
        *(bf16x8*)&sB[wave][r*136 + s*32 + g*8] = ah;
    }

    // ---- gemm1: acc = tfeat@W_in + Hsum@W_ctx2  (s-outer; data in regs/LDS)
    floatx4 acc[8];
#pragma unroll
    for (int t = 0; t < 8; ++t) acc[t] = (floatx4){0.f,0.f,0.f,0.f};
#pragma unroll
    for (int s = 0; s < 4; ++s) {
        bf16x8 aH = *(const bf16x8*)&sB[wave][r*136 + s*32 + g*8];
#pragma unroll
        for (int t = 0; t < 8; ++t) {
            bf16x8 bF = *(const bf16x8*)&swC2[((t*4+s)*64 + lane)*8];
            acc[t] = __builtin_amdgcn_mfma_f32_16x16x32_bf16(aH, bF, acc[t], 0, 0, 0);
        }
        float4 v0 = p[2*s], v1 = p[2*s+1];
        bf16x8 aF = { (bf16_t)v0.x, (bf16_t)v0.y, (bf16_t)v0.z, (bf16_t)v0.w,
                      (bf16_t)v1.x, (bf16_t)v1.y, (bf16_t)v1.z, (bf16_t)v1.w };
#pragma unroll
        for (int t = 0; t < 8; ++t) {
            bf16x8 bF = *(const bf16x8*)&swIn[((t*4+s)*64 + lane)*8];
            acc[t] = __builtin_amdgcn_mfma_f32_16x16x32_bf16(aF, bF, acc[t], 0, 0, 0);
        }
    }
    gn_rows(acc, lane, g_n, be_n, true);

    // ---- restage -> gemm2 (W_m1)
#pragma unroll
    for (int t = 0; t < 8; ++t)
#pragma unroll
        for (int rr = 0; rr < 4; ++rr)
            sB[wave][(g*4 + rr)*136 + t*16 + r] = (bf16_t)acc[t][rr];
#pragma unroll
    for (int t = 0; t < 8; ++t) acc[t] = (floatx4){0.f,0.f,0.f,0.f};
#pragma unroll
    for (int s = 0; s < 4; ++s) {
        bf16x8 aF = *(const bf16x8*)&sB[wave][r*136 + s*32 + g*8];
#pragma unroll
        for (int t = 0; t < 8; ++t) {
            bf16x8 bF = *(const bf16x8*)&swM1[((t*4+s)*64 + lane)*8];
            acc[t] = __builtin_amdgcn_mfma_f32_16x16x32_bf16(aF, bF, acc[t], 0, 0, 0);
        }
    }
    gn_rows(acc, lane, g_m1, be_m1, true);

    // ---- restage -> gemm3 (W_m2)
#pragma unroll
    for (int t = 0; t < 8; ++t)
#pragma unroll
        for (int rr = 0; rr < 4; ++rr)
            sB[wave][(g*4 + rr)*136 + t*16 + r] = (bf16_t)acc[t][rr];
#pragma unroll
    for (int t = 0; t < 8; ++t) acc[t] = (floatx4){0.f,0.f,0.f,0.f};
#pragma unroll
    for (int s = 0; s < 4; ++s) {
        bf16x8 aF = *(const bf16x8*)&sB[wave][r*136 + s*32 + g*8];
#pragma unroll
        for (int t = 0; t < 8; ++t) {
            bf16x8 bF = *(const bf16x8*)&swM2[((t*4+s)*64 + lane)*8];
            acc[t] = __builtin_amdgcn_mfma_f32_16x16x32_bf16(aF, bF, acc[t], 0, 0, 0);
        }
    }
    gn_rows(acc, lane, g_m2, be_m2, false);

    // ---- epilogue: +identity, relu, direct C-layout stores (64B segments)
#pragma unroll
    for (int t = 0; t < 8; ++t) {
        int n = t*16 + r;
#pragma unroll
        for (int rr = 0; rr < 4; ++rr) {
            int row = tb + g*4 + rr;
            if (row < Nt) {
                float v = acc[t][rr] + tfeat[(size_t)row*128 + n];
                out[(size_t)row*128 + n] = fmaxf(v, 0.f);
            }
        }
    }
}

// ===========================================================================
// FALLBACK PATH (previous kernels, used only if workspace is too small for
// the binned h buffer).
// ===========================================================================
__global__ __launch_bounds__(256) void k_gemm_in(
    const float* __restrict__ tfeat, const bf16_t* __restrict__ swW,
    float* __restrict__ tf, int Nt)
{
    __shared__ alignas(16) bf16_t sA[4][2048];
    int tid = threadIdx.x, lane = tid & 63, wave = tid >> 6;

    int tb = (blockIdx.x * 4 + wave) * 16;
    int r = lane >> 2, cb = (lane & 3) * 32;
    int grow = tb + r;
    bool rv = grow < Nt;
    const float4* src = (const float4*)(tfeat + (size_t)(rv ? grow : 0) * 128 + cb);
#pragma unroll
    for (int i = 0; i < 8; ++i) {
        float4 v = rv ? src[i] : make_float4(0.f,0.f,0.f,0.f);
        int k = cb + 4*i;
        int s = k >> 5, q = (k >> 3) & 3, j = k & 7;
        bf16x4 pk = { (bf16_t)v.x, (bf16_t)v.y, (bf16_t)v.z, (bf16_t)v.w };
        *(bf16x4*)&sA[wave][(s*64 + q*16 + r)*8 + j] = pk;
    }
    __syncthreads();
    int m = lane & 15, g = lane >> 4;
    bf16x8 aF[4];
#pragma unroll
    for (int s = 0; s < 4; ++s) aF[s] = *(const bf16x8*)&sA[wave][(s*64 + lane)*8];
#pragma unroll
    for (int t = 0; t < 8; ++t) {
        floatx4 a = {0.f,0.f,0.f,0.f};
#pragma unroll
        for (int s = 0; s < 4; ++s) {
            bf16x8 bF = *(const bf16x8*)&swW[((t*4+s)*64 + lane)*8];
            a = __builtin_amdgcn_mfma_f32_16x16x32_bf16(aF[s], bF, a, 0, 0, 0);
        }
#pragma unroll
        for (int rr = 0; rr < 4; ++rr) {
            int row = tb + g*4 + rr;
            if (row < Nt) tf[(size_t)row*128 + t*16 + m] = a[rr];
        }
    }
}

__global__ __launch_bounds__(256) void k_edge_old(
    const float* __restrict__ cfeat, const float* __restrict__ cpose,
    const float* __restrict__ tpose, const int* __restrict__ hi,
    const int* __restrict__ wi, const float* __restrict__ W_rp,
    const float* __restrict__ b_rp, const float* __restrict__ g_ctx,
    const float* __restrict__ be_ctx, const bf16_t* __restrict__ swC1,
    const bf16_t* __restrict__ swC2, float* __restrict__ tf, int E)
{
    __shared__ alignas(16) bf16_t sA[4][4096];
    int tid = threadIdx.x, lane = tid & 63, wave = tid >> 6;

    int tb = (blockIdx.x * 4 + wave) * 16;
    int r = lane >> 2, cb = (lane & 3) * 32;
    int e = min(tb + r, E - 1);
    int ci = hi[e], ti = wi[e];
    const float4* src = (const float4*)(cfeat + (size_t)ci * 128 + cb);
#pragma unroll
    for (int i = 0; i < 8; ++i) {
        float4 v = src[i];
        int k = cb + 4*i;
        int s = k >> 5, q = (k >> 3) & 3, j = k & 7;
        bf16x4 pk = { (bf16_t)v.x, (bf16_t)v.y, (bf16_t)v.z, (bf16_t)v.w };
        *(bf16x4*)&sA[wave][(s*64 + q*16 + r)*8 + j] = pk;
    }
    float4 cp = ((const float4*)cpose)[ci];
    float4 tp = ((const float4*)tpose)[ti];
    float d0 = cp.x - tp.x, d1 = cp.y - tp.y, d2 = cp.z - tp.z, d3 = cp.w - tp.w;
#pragma unroll
    for (int i = 0; i < 8; ++i) {
        int cc = cb + 4*i;
        float4 w0 = *(const float4*)(W_rp + cc);
        float4 w1 = *(const float4*)(W_rp + 128 + cc);
        float4 w2 = *(const float4*)(W_rp + 256 + cc);
        float4 w3 = *(const float4*)(W_rp + 384 + cc);
        float4 bb = *(const float4*)(b_rp + cc);
        float o0 = fmaxf(d0*w0.x + d1*w1.x + d2*w2.x + d3*w3.x + bb.x, 0.f);
        float o1 = fmaxf(d0*w0.y + d1*w1.y + d2*w2.y + d3*w3.y + bb.y, 0.f);
        float o2 = fmaxf(d0*w0.z + d1*w1.z + d2*w2.z + d3*w3.z + bb.z, 0.f);
        float o3 = fmaxf(d0*w0.w + d1*w1.w + d2*w2.w + d3*w3.w + bb.w, 0.f);
        int k = 128 + cc;
        int s = k >> 5, q = (k >> 3) & 3, j = k & 7;
        bf16x4 pk = { (bf16_t)o0, (bf16_t)o1, (bf16_t)o2, (bf16_t)o3 };
        *(bf16x4*)&sA[wave][(s*64 + q*16 + r)*8 + j] = pk;
    }
    __syncthreads();

    int m = lane & 15, g = lane >> 4;
    bf16x8 aF[8];
#pragma unroll
    for (int s = 0; s < 8; ++s) aF[s] = *(const bf16x8*)&sA[wave][(s*64 + lane)*8];
    floatx4 acc[8];
#pragma unroll
    for (int t = 0; t < 8; ++t) {
        floatx4 a = {0.f,0.f,0.f,0.f};
#pragma unroll
        for (int s = 0; s < 8; ++s) {
            bf16x8 bF = *(const bf16x8*)&swC1[(size_t)((t*8+s)*64 + lane)*8];
            a = __builtin_amdgcn_mfma_f32_16x16x32_bf16(aF[s], bF, a, 0, 0, 0);
        }
        acc[t] = a;
    }
    gn_rows(acc, lane, g_ctx, be_ctx, true);
    __syncthreads();
#pragma unroll
    for (int t = 0; t < 8; ++t) {
        int n = t*16 + m;
        int s = n >> 5, q = (n >> 3) & 3, j = n & 7;
#pragma unroll
        for (int rr = 0; rr < 4; ++rr)
            sA[wave][(s*64 + q*16 + (g*4+rr))*8 + j] = (bf16_t)acc[t][rr];
    }
    __syncthreads();
    bf16x8 aF2[4];
#pragma unroll
    for (int s = 0; s < 4; ++s) aF2[s] = *(const bf16x8*)&sA[wave][(s*64 + lane)*8];
    int dstrow[4]; bool vald[4];
#pragma unroll
    for (int rr = 0; rr < 4; ++rr) {
        int ee = tb + g*4 + rr;
        vald[rr] = ee < E;
        dstrow[rr] = vald[rr] ? wi[ee] : 0;
    }
#pragma unroll
    for (int t = 0; t < 8; ++t) {
        floatx4 a = {0.f,0.f,0.f,0.f};
#pragma unroll
        for (int s = 0; s < 4; ++s) {
            bf16x8 bF = *(const bf16x8*)&swC2[((t*4+s)*64 + lane)*8];
            a = __builtin_amdgcn_mfma_f32_16x16x32_bf16(aF2[s], bF, a, 0, 0, 0);
        }
#pragma unroll
        for (int rr = 0; rr < 4; ++rr) {
            if (vald[rr])
                atomicAdd(&tf[(size_t)dstrow[rr]*128 + t*16 + m], a[rr]);
        }
    }
}

__global__ __launch_bounds__(256) void k_out_old(
    const float* __restrict__ tf, const float* __restrict__ identity,
    const float* __restrict__ g_n, const float* __restrict__ be_n,
    const float* __restrict__ g_m1, const float* __restrict__ be_m1,
    const float* __restrict__ g_m2, const float* __restrict__ be_m2,
    const bf16_t* __restrict__ swM1, const bf16_t* __restrict__ swM2,
    float* __restrict__ out, int Nt)
{
    __shared__ alignas(16) bf16_t sA[4][2048];
    int tid = threadIdx.x, lane = tid & 63, wave = tid >> 6;

    int tb = (blockIdx.x*4 + wave)*16;
    int r = lane >> 2, cb = (lane & 3)*32;
    int grow = tb + r;
    bool rv = grow < Nt;
    const float4* src = (const float4*)(tf + (size_t)(rv ? grow : 0)*128 + cb);
    float vals[32];
    float ls = 0.f, lq = 0.f;
#pragma unroll
    for (int i = 0; i < 8; ++i) {
        float4 v = rv ? src[i] : make_float4(0.f,0.f,0.f,0.f);
        vals[4*i+0]=v.x; vals[4*i+1]=v.y; vals[4*i+2]=v.z; vals[4*i+3]=v.w;
        ls += v.x+v.y+v.z+v.w;
        lq += v.x*v.x+v.y*v.y+v.z*v.z+v.w*v.w;
    }
    ls += __shfl_xor(ls,1); lq += __shfl_xor(lq,1);
    ls += __shfl_xor(ls,2); lq += __shfl_xor(lq,2);
    float mean = ls*(1.f/128.f);
    float inv = rsqrtf(lq*(1.f/128.f) - mean*mean + EPSF);
#pragma unroll
    for (int i = 0; i < 8; ++i) {
        int cc = cb + 4*i;
        float4 ga = *(const float4*)(g_n + cc);
        float4 be = *(const float4*)(be_n + cc);
        float o0 = fmaxf((vals[4*i+0]-mean)*inv*ga.x + be.x, 0.f);
        float o1 = fmaxf((vals[4*i+1]-mean)*inv*ga.y + be.y, 0.f);
        float o2 = fmaxf((vals[4*i+2]-mean)*inv*ga.z + be.z, 0.f);
        float o3 = fmaxf((vals[4*i+3]-mean)*inv*ga.w + be.w, 0.f);
        int s = cc >> 5, q = (cc >> 3) & 3, j = cc & 7;
        bf16x4 pk = { (bf16_t)o0, (bf16_t)o1, (bf16_t)o2, (bf16_t)o3 };
        *(bf16x4*)&sA[wave][(s*64 + q*16 + r)*8 + j] = pk;
    }
    __syncthreads();
    int m = lane & 15, g = lane >> 4;
    bf16x8 aF[4];
#pragma unroll
    for (int s = 0; s < 4; ++s) aF[s] = *(const bf16x8*)&sA[wave][(s*64 + lane)*8];
    floatx4 acc[8];
#pragma unroll
    for (int t = 0; t < 8; ++t) {
        floatx4 a = {0.f,0.f,0.f,0.f};
#pragma unroll
        for (int s = 0; s < 4; ++s) {
            bf16x8 bF = *(const bf16x8*)&swM1[((t*4+s)*64 + lane)*8];
            a = __builtin_amdgcn_mfma_f32_16x16x32_bf16(aF[s], bF, a, 0, 0, 0);
        }
        acc[t] = a;
    }
    gn_rows(acc, lane, g_m1, be_m1, true);
    __syncthreads();
#pragma unroll
    for (int t = 0; t < 8; ++t) {
        int n = t*16 + m;
        int s = n >> 5, q = (n >> 3) & 3, j = n & 7;
#pragma unroll
        for (int rr = 0; rr < 4; ++rr)
            sA[wave][(s*64 + q*16 + (g*4+rr))*8 + j] = (bf16_t)acc[t][rr];
    }
    __syncthreads();
#pragma unroll
    for (int s = 0; s < 4; ++s) aF[s] = *(const bf16x8*)&sA[wave][(s*64 + lane)*8];
#pragma unroll
    for (int t = 0; t < 8; ++t) {
        floatx4 a = {0.f,0.f,0.f,0.f};
#pragma unroll
        for (int s = 0; s < 4; ++s) {
            bf16x8 bF = *(const bf16x8*)&swM2[((t*4+s)*64 + lane)*8];
            a = __builtin_amdgcn_mfma_f32_16x16x32_bf16(aF[s], bF, a, 0, 0, 0);
        }
        acc[t] = a;
    }
    gn_rows(acc, lane, g_m2, be_m2, false);
#pragma unroll
    for (int t = 0; t < 8; ++t) {
        int n = t*16 + m;
#pragma unroll
        for (int rr = 0; rr < 4; ++rr) {
            int row = tb + g*4 + rr;
            if (row < Nt) {
                float v = acc[t][rr] + identity[(size_t)row*128 + n];
                out[(size_t)row*128 + n] = fmaxf(v, 0.f);
            }
        }
    }
}

// ---------------------------------------------------------------------------
extern "C" void kernel_launch(void* const* d_in, const int* in_sizes, int n_in,
                              void* d_out, int out_size, void* d_ws, size_t ws_size,
                              hipStream_t stream)
{
    const float* cfeat  = (const float*)d_in[0];
    const float* tfeat  = (const float*)d_in[1];
    const float* cpose  = (const float*)d_in[2];
    const float* tpose  = (const float*)d_in[3];
    const int*   hi     = (const int*)d_in[4];
    const int*   wi     = (const int*)d_in[5];
    const float* W_in   = (const float*)d_in[6];
    const float* W_rp   = (const float*)d_in[7];
    const float* b_rp   = (const float*)d_in[8];
    const float* W_ctx1 = (const float*)d_in[9];
    const float* g_ctx  = (const float*)d_in[10];
    const float* be_ctx = (const float*)d_in[11];
    const float* W_ctx2 = (const float*)d_in[12];
    const float* g_n    = (const float*)d_in[13];
    const float* be_n   = (const float*)d_in[14];
    const float* W_m1   = (const float*)d_in[15];
    const float* g_m1   = (const float*)d_in[16];
    const float* be_m1  = (const float*)d_in[17];
    const float* W_m2   = (const float*)d_in[18];
    const float* g_m2   = (const float*)d_in[19];
    const float* be_m2  = (const float*)d_in[20];

    int Nt = in_sizes[1] / 128;
    int E  = in_sizes[4];
    float* outp = (float*)d_out;

    // new-path workspace layout
    char* base = (char*)d_ws;
    size_t o = 98304 * sizeof(bf16_t);                 // sw @ 0
    o = (o + 255) & ~(size_t)255;
    size_t o_cnt = o; o += (size_t)Nt * 4;             // wi histogram
    o = (o + 255) & ~(size_t)255;
    size_t o_off = o; o += ((size_t)Nt + 1) * 4;       // wi offsets
    o = (o + 255) & ~(size_t)255;
    size_t o_cur = o; o += (size_t)Nt * 4;             // wi slot cursors
    o = (o + 255) & ~(size_t)255;
    size_t o_bsum = o; o += 1024 * 4;                  // scan block sums
    o = (o + 255) & ~(size_t)255;
    size_t o_dst = o; o += (size_t)E * 4;              // per-edge slot
    o = (o + 255) & ~(size_t)255;
    size_t o_h = o; o += (size_t)E * 128 * sizeof(bf16_t);

    int NB = (Nt + 4095) / 4096;                       // scan blocks (<=1024)

    if (ws_size >= o && NB <= 1024) {
        bf16_t* sw    = (bf16_t*)base;
        int*    cnt   = (int*)(base + o_cnt);
        int*    off   = (int*)(base + o_off);
        int*    cur   = (int*)(base + o_cur);
        int*    bsum  = (int*)(base + o_bsum);
        int*    dst   = (int*)(base + o_dst);
        bf16_t* hbuf  = (bf16_t*)(base + o_h);
        bf16_t* swIn = sw;
        bf16_t* swC1 = sw + 16384;
        bf16_t* swC2 = sw + 49152;
        bf16_t* swM1 = sw + 65536;
        bf16_t* swM2 = sw + 81920;

        hipMemsetAsync(cnt, 0, (size_t)Nt * 4, stream);
        hipMemsetAsync(cur, 0, (size_t)Nt * 4, stream);
        k_prep<<<384, 256, 0, stream>>>(W_in, W_ctx1, W_ctx2, W_m1, W_m2, sw);
        k_count<<<(E + 255) / 256, 256, 0, stream>>>(wi, cnt, E);
        k_scanA<<<NB, 1024, 0, stream>>>(cnt, off, bsum, Nt);
        k_scanB<<<1, 1024, 0, stream>>>(bsum, off, NB, Nt);
        k_scanC<<<(Nt + 255) / 256, 256, 0, stream>>>(off, bsum, Nt);
        k_slots<<<(E + 255) / 256, 256, 0, stream>>>(wi, off, cur, dst, E);
        k_edge10<<<(E + 63) / 64, 256, 0, stream>>>(cfeat, cpose, tpose, hi, wi,
                                                    dst, W_rp, b_rp, g_ctx, be_ctx,
                                                    swC1, hbuf, E);
        k_out3<<<(Nt + 63) / 64, 256, 0, stream>>>(tfeat, hbuf, off,
                                                   g_n, be_n, g_m1, be_m1,
                                                   g_m2, be_m2,
                                                   swIn, swC2, swM1, swM2,
                                                   outp, Nt);
    } else {
        // fallback: previous atomic-scatter path
        float*  tf = (float*)d_ws;                                   // [Nt,128] f32
        bf16_t* sw = (bf16_t*)((char*)d_ws + (size_t)Nt * 128 * sizeof(float));
        bf16_t* swIn = sw;
        bf16_t* swC1 = sw + 16384;
        bf16_t* swC2 = sw + 49152;
        bf16_t* swM1 = sw + 65536;
        bf16_t* swM2 = sw + 81920;

        k_prep<<<384, 256, 0, stream>>>(W_in, W_ctx1, W_ctx2, W_m1, W_m2, sw);
        k_gemm_in<<<(Nt + 63) / 64, 256, 0, stream>>>(tfeat, swIn, tf, Nt);
        k_edge_old<<<(E + 63) / 64, 256, 0, stream>>>(cfeat, cpose, tpose, hi, wi,
                                                      W_rp, b_rp, g_ctx, be_ctx,
                                                      swC1, swC2, tf, E);
        k_out_old<<<(Nt + 63) / 64, 256, 0, stream>>>(tf, tfeat, g_n, be_n,
                                                      g_m1, be_m1, g_m2, be_m2,
                                                      swM1, swM2, outp, Nt);
    }
}